// Round 1
// baseline (61.286 us; speedup 1.0000x reference)
//
#include <hip/hip_runtime.h>

#define GG 1000
#define NPG 500
#define KK 8
#define N1 128
#define N2 128
#define NEG_SLOPE 0.45f
#define NTHREADS 512
#define NWAVES 8

__global__ __launch_bounds__(NTHREADS) void cluster_attn_kernel(
    const float* __restrict__ x,
    const float* __restrict__ W1,
    const float* __restrict__ b1,
    const float* __restrict__ Wa,
    const float* __restrict__ ba,
    const int*   __restrict__ cls,
    float*       __restrict__ out)
{
    // Wave-private accumulators (no atomics): 8 waves x 8 clusters x 128 feats
    __shared__ float s_acc[NWAVES][KK][N1];   // 32 KB; s_acc[0] becomes final csum
    __shared__ float s_cnt[NWAVES][KK];
    __shared__ float s_fcnt[KK];
    __shared__ float s_ratio[KK];
    __shared__ float s_L[KK];
    __shared__ float s_e[KK];

    const int g   = blockIdx.x;
    const int tid = threadIdx.x;
    const int w   = tid >> 6;     // wave id 0..7
    const int l   = tid & 63;     // lane id

    float* accf = &s_acc[0][0][0];

    // ---- zero accumulators ----
    for (int i = tid; i < NWAVES * KK * N1; i += NTHREADS) accf[i] = 0.f;
    if (tid < NWAVES * KK) s_cnt[tid >> 3][tid & 7] = 0.f;
    __syncthreads();

    // ---- phase 1: per-wave cluster sums over this graph's 500 nodes ----
    const float2* x2   = (const float2*)(x + (size_t)g * NPG * N1);
    const int*    clsg = cls + (size_t)g * NPG;
    float2* accw = (float2*)&s_acc[w][0][0];

    for (int n = w; n < NPG; n += NWAVES) {
        int c = clsg[n];                       // broadcast load
        float2 v = x2[(size_t)n * 64 + l];     // 512B coalesced per wave
        float2* p = accw + c * 64 + l;         // lane-private address in wave copy
        float2 cur = *p;
        cur.x += v.x; cur.y += v.y;
        *p = cur;
        if (l == 0) s_cnt[w][c] += 1.f;        // wave-private, lane 0 only
    }
    __syncthreads();

    // ---- reduce 8 wave copies into s_acc[0]; counts + ratios by thread 0 ----
    for (int e = tid; e < KK * N1; e += NTHREADS) {
        float s = 0.f;
        #pragma unroll
        for (int ww = 0; ww < NWAVES; ++ww) s += s_acc[ww][0][e];
        accf[e] = s;   // read-before-write on own element only: safe
    }
    if (tid == 0) {
        float d = 0.f;
        #pragma unroll
        for (int k = 0; k < KK; ++k) {
            float c = 0.f;
            #pragma unroll
            for (int ww = 0; ww < NWAVES; ++ww) c += s_cnt[ww][k];
            s_fcnt[k] = c;
            d += c * c;                        // denom = sum_k c_k^2
        }
        #pragma unroll
        for (int k = 0; k < KK; ++k) s_ratio[k] = s_fcnt[k] / d;
    }
    __syncthreads();

    // ---- phase 2: h[k][j] = leaky(ratio_k * (csum_k . W1[:,j]) + b1[j]);
    //      hw[k][j] = h[k][j] * Wa[j]  (1024 dot products over 512 threads) ----
    float* s_hw = &s_acc[1][0][0];             // reuse wave-copy 1 region (1024 f32)
    #pragma unroll
    for (int r = 0; r < 2; ++r) {
        int idx = tid + r * NTHREADS;          // 0..1023
        int k = idx >> 7;
        int j = idx & 127;
        float s = 0.f;
        #pragma unroll 4
        for (int f = 0; f < N1; ++f)
            s = fmaf(accf[k * N1 + f], W1[f * N2 + j], s);  // LDS broadcast x coalesced W1
        float val = fmaf(s, s_ratio[k], b1[j]);
        float h = val > 0.f ? val : NEG_SLOPE * val;
        s_hw[idx] = h * Wa[j];
    }
    __syncthreads();

    // ---- per-k reduce: wave w owns cluster k=w ----
    {
        float v = s_hw[w * 128 + l] + s_hw[w * 128 + 64 + l];
        #pragma unroll
        for (int off = 32; off > 0; off >>= 1) v += __shfl_down(v, off);
        if (l == 0) s_L[w] = v + ba[0];
    }
    __syncthreads();

    // ---- phase 3: count-weighted softmax over 8 clusters (skip empty) ----
    if (tid == 0) {
        float m = -1e30f;
        #pragma unroll
        for (int k = 0; k < KK; ++k)
            if (s_fcnt[k] > 0.f) m = fmaxf(m, s_L[k]);
        float ssum = 0.f;
        float ek[KK];
        #pragma unroll
        for (int k = 0; k < KK; ++k) {
            ek[k] = (s_fcnt[k] > 0.f) ? expf(s_L[k] - m) : 0.f;
            ssum += s_fcnt[k] * ek[k];
        }
        #pragma unroll
        for (int k = 0; k < KK; ++k) s_e[k] = ek[k] / ssum;
    }
    __syncthreads();

    // ---- phase 4: per-node output = table lookup ----
    float* outg = out + (size_t)g * NPG;
    for (int n = tid; n < NPG; n += NTHREADS) outg[n] = s_e[clsg[n]];
}

extern "C" void kernel_launch(void* const* d_in, const int* in_sizes, int n_in,
                              void* d_out, int out_size, void* d_ws, size_t ws_size,
                              hipStream_t stream) {
    const float* x   = (const float*)d_in[0];
    const float* W1  = (const float*)d_in[1];
    const float* b1  = (const float*)d_in[2];
    const float* Wa  = (const float*)d_in[3];
    const float* ba  = (const float*)d_in[4];
    const int*   cls = (const int*)d_in[5];
    // d_in[6] = batch: sorted repeat(arange(G), NPG) by construction -> implicit

    float* out = (float*)d_out;
    cluster_attn_kernel<<<GG, NTHREADS, 0, stream>>>(x, W1, b1, Wa, ba, cls, out);
}